// Round 4
// baseline (458.877 us; speedup 1.0000x reference)
//
#include <hip/hip_runtime.h>

// CRF loss: mean over batch of (logZ - path_score).  B=512, T=1024, K=48.
//
// Forward pass: 16 sequences per wave, 32 waves. Scaled linear-domain
// recurrence as a 48x48 @ 48x16 MFMA matmul per step:
//   Q' = (expT @ Q) .* expE_t,  per-column running log-scale c.
// Key layout identity for v_mfma_f32_16x16x16_bf16: the C/D mapping
// (n=lane&15, m=4*(lane>>4)+reg) equals the B-operand mapping
// (n=lane&15, k=4*(lane>>4)+j), so D feeds the next step's B with a purely
// per-lane transform: multiply by exp(emission) in fp32, pack to bf16.
// A (= exp(transition), bf16) is fixed in 18 VGPRs for the whole run.
// Per-column rescale every 8 steps bounds fp32/bf16 range (growth <= ~4e3^8).
// Ragged lengths: capture logZ_n at t == len_n-1 (ballot-guarded; the 4 lane
// replicas of a column share len_n so the xor-16/32 shuffles are safe).
// Path-score blocks (32..543) share the launch and overlap the forward waves.

#define BB   512
#define TT   1024
#define KK   48
#define GG   16
#define NGRP 32     // BB / GG

typedef __attribute__((ext_vector_type(4))) short bf16x4;
typedef __attribute__((ext_vector_type(4))) float f32x4;

__device__ __forceinline__ f32x4 mfma16(bf16x4 a, bf16x4 b, f32x4 c) {
#if __has_builtin(__builtin_amdgcn_mfma_f32_16x16x16bf16_1k)
    return __builtin_amdgcn_mfma_f32_16x16x16bf16_1k(a, b, c, 0, 0, 0);
#else
    f32x4 d;
    asm volatile("v_mfma_f32_16x16x16_bf16 %0, %1, %2, %3"
                 : "=v"(d) : "v"(a), "v"(b), "v"(c));
    return d;
#endif
}

// pack two fp32 -> one dword of two bf16 (round-half-up via +0x8000, then
// v_perm_b32 selects the high halves; lo lands in bits [15:0])
__device__ __forceinline__ unsigned pk2(float lo, float hi) {
    return __builtin_amdgcn_perm(__float_as_uint(hi) + 0x8000u,
                                 __float_as_uint(lo) + 0x8000u,
                                 0x07060302u);
}
__device__ __forceinline__ bf16x4 pack4(float a, float b, float c, float d) {
    union { unsigned u[2]; bf16x4 v; } x;
    x.u[0] = pk2(a, b);
    x.u[1] = pk2(c, d);
    return x.v;
}

__device__ __forceinline__ float wave_reduce_sum(float v) {
    #pragma unroll
    for (int off = 32; off > 0; off >>= 1)
        v += __shfl_xor(v, off, 64);
    return v;
}

__global__ __launch_bounds__(64, 1) void crf_main_kernel(
    const float* __restrict__ emis,    // [B,T,K]
    const int*   __restrict__ lengths, // [B]
    const int*   __restrict__ tags,    // [B,T]
    const float* __restrict__ prior,   // [K]
    const float* __restrict__ trans,   // [K,K] trans[dest][src]
    const float* __restrict__ finalT,  // [K]
    float*       __restrict__ ws)      // [0..511] logZ, [512..1023] path
{
    const int lane = threadIdx.x;

    // ================= path-score blocks =================
    if (blockIdx.x >= NGRP) {
        const int b = blockIdx.x - NGRP;
        int len = lengths[b];
        len = (len < 1) ? 1 : (len > TT ? TT : len);
        const float* eb = emis + (size_t)b * TT * KK;
        const int*   tg = tags + (size_t)b * TT;
        float ps = 0.0f;
        for (int t = lane; t < len; t += 64) {
            int cur = tg[t];
            float ev = eb[(size_t)t * KK + cur];
            float tr = (t == 0) ? prior[cur] : trans[cur * KK + tg[t - 1]];
            ps += ev + tr;
        }
        ps = wave_reduce_sum(ps);
        float fin = finalT[tg[len - 1]];
        if (lane == 0) ws[BB + b] = ps + fin;
        return;
    }

    // ================= forward (MFMA) blocks =================
    const int g     = blockIdx.x;
    const int col   = lane & 15;      // sequence within group == matrix col n
    const int grp   = lane >> 4;      // row-group 0..3
    const int rbase = grp * 4;        // row offset inside a 16-tile
    const int seq   = g * GG + col;

    int len = lengths[seq];
    len = (len < 1) ? 1 : (len > TT ? TT : len);
    const int lenn1 = len - 1;
    int gmax = len;
    #pragma unroll
    for (int off = 32; off > 0; off >>= 1) {
        int o = __shfl_xor(gmax, off, 64);
        gmax = (o > gmax) ? o : gmax;
    }

    // ---- A tiles: bf16(exp(trans)); A[m][k]: m = mt*16+col, k = kt*16+rbase+j
    bf16x4 A[3][3];
    #pragma unroll
    for (int mt = 0; mt < 3; ++mt) {
        #pragma unroll
        for (int kt = 0; kt < 3; ++kt) {
            float4 tv = *reinterpret_cast<const float4*>(
                trans + (size_t)(mt * 16 + col) * KK + kt * 16 + rbase);
            A[mt][kt] = pack4(__expf(tv.x), __expf(tv.y),
                              __expf(tv.z), __expf(tv.w));
        }
    }

    // ---- per-lane row constants: rows m = mt*16 + rbase + j ----
    float expF[12], pri[12];
    #pragma unroll
    for (int mt = 0; mt < 3; ++mt) {
        float4 fv = *reinterpret_cast<const float4*>(finalT + mt * 16 + rbase);
        expF[mt*4+0] = __expf(fv.x); expF[mt*4+1] = __expf(fv.y);
        expF[mt*4+2] = __expf(fv.z); expF[mt*4+3] = __expf(fv.w);
        float4 pv = *reinterpret_cast<const float4*>(prior + mt * 16 + rbase);
        pri[mt*4+0] = pv.x; pri[mt*4+1] = pv.y;
        pri[mt*4+2] = pv.z; pri[mt*4+3] = pv.w;
    }

    const float* ebase = emis + (size_t)seq * TT * KK + rbase;

    // ---- init (t=0): w = exp(E0 + prior - c), c = per-column max ----
    float w[12];
    float c;
    float zcap = 0.0f;
    {
        float a0[12];
        #pragma unroll
        for (int mt = 0; mt < 3; ++mt) {
            float4 ev = *reinterpret_cast<const float4*>(ebase + mt * 16);
            a0[mt*4+0] = ev.x + pri[mt*4+0];
            a0[mt*4+1] = ev.y + pri[mt*4+1];
            a0[mt*4+2] = ev.z + pri[mt*4+2];
            a0[mt*4+3] = ev.w + pri[mt*4+3];
        }
        float mx = a0[0];
        #pragma unroll
        for (int r = 1; r < 12; ++r) mx = fmaxf(mx, a0[r]);
        mx = fmaxf(mx, __shfl_xor(mx, 16, 64));
        mx = fmaxf(mx, __shfl_xor(mx, 32, 64));
        c = mx;
        #pragma unroll
        for (int r = 0; r < 12; ++r) w[r] = __expf(a0[r] - c);
        if (__ballot(lenn1 == 0)) {
            float S = 0.0f;
            #pragma unroll
            for (int r = 0; r < 12; ++r) S = fmaf(w[r], expF[r], S);
            S += __shfl_xor(S, 16, 64);
            S += __shfl_xor(S, 32, 64);
            if (lenn1 == 0) zcap = c + __logf(S);
        }
    }

    bf16x4 Bt[3];
    Bt[0] = pack4(w[0], w[1], w[2],  w[3]);
    Bt[1] = pack4(w[4], w[5], w[6],  w[7]);
    Bt[2] = pack4(w[8], w[9], w[10], w[11]);

    // ---- emission prefetch pipeline, depth 6 (3 x float4 per step) ----
    float4 P[6][3];
    #pragma unroll
    for (int s = 0; s < 6; ++s) {
        int tc = 1 + s; if (tc > gmax - 1) tc = gmax - 1;
        const float* ep = ebase + (size_t)tc * KK;
        P[s][0] = *reinterpret_cast<const float4*>(ep);
        P[s][1] = *reinterpret_cast<const float4*>(ep + 16);
        P[s][2] = *reinterpret_cast<const float4*>(ep + 32);
    }

    const f32x4 zero4 = {0.f, 0.f, 0.f, 0.f};
    int t = 1;
    while (t < gmax) {
        #pragma unroll
        for (int s = 0; s < 6; ++s) {
            // ---- Q' = expT @ Q : 9 MFMAs, 3 independent acc chains ----
            f32x4 D0 = mfma16(A[0][0], Bt[0], zero4);
            f32x4 D1 = mfma16(A[1][0], Bt[0], zero4);
            f32x4 D2 = mfma16(A[2][0], Bt[0], zero4);
            D0 = mfma16(A[0][1], Bt[1], D0);
            D1 = mfma16(A[1][1], Bt[1], D1);
            D2 = mfma16(A[2][1], Bt[1], D2);
            D0 = mfma16(A[0][2], Bt[2], D0);
            D1 = mfma16(A[1][2], Bt[2], D1);
            D2 = mfma16(A[2][2], Bt[2], D2);

            // ---- apply emissions (fp32), D-layout == B-layout ----
            w[0]  = D0.x * __expf(P[s][0].x);
            w[1]  = D0.y * __expf(P[s][0].y);
            w[2]  = D0.z * __expf(P[s][0].z);
            w[3]  = D0.w * __expf(P[s][0].w);
            w[4]  = D1.x * __expf(P[s][1].x);
            w[5]  = D1.y * __expf(P[s][1].y);
            w[6]  = D1.z * __expf(P[s][1].z);
            w[7]  = D1.w * __expf(P[s][1].w);
            w[8]  = D2.x * __expf(P[s][2].x);
            w[9]  = D2.y * __expf(P[s][2].y);
            w[10] = D2.z * __expf(P[s][2].z);
            w[11] = D2.w * __expf(P[s][2].w);

            // ---- refill slot s for step t+6 (clamped; in-bounds always) ----
            {
                int tc = t + 6; if (tc > gmax - 1) tc = gmax - 1;
                const float* ep = ebase + (size_t)tc * KK;
                P[s][0] = *reinterpret_cast<const float4*>(ep);
                P[s][1] = *reinterpret_cast<const float4*>(ep + 16);
                P[s][2] = *reinterpret_cast<const float4*>(ep + 32);
            }

            // ---- per-column rescale every 8 steps ----
            if ((t & 7) == 0) {
                float mx = w[0];
                #pragma unroll
                for (int r = 1; r < 12; ++r) mx = fmaxf(mx, w[r]);
                mx = fmaxf(mx, __shfl_xor(mx, 16, 64));
                mx = fmaxf(mx, __shfl_xor(mx, 32, 64));
                c += __logf(mx);
                float rm = __builtin_amdgcn_rcpf(mx);
                #pragma unroll
                for (int r = 0; r < 12; ++r) w[r] *= rm;
            }

            // ---- capture finished columns (rare; ballot-guarded) ----
            if (__ballot(t == lenn1)) {
                float S = 0.0f;
                #pragma unroll
                for (int r = 0; r < 12; ++r) S = fmaf(w[r], expF[r], S);
                S += __shfl_xor(S, 16, 64);
                S += __shfl_xor(S, 32, 64);
                if (t == lenn1) zcap = c + __logf(S);
            }

            // ---- repack state for next step's B operand ----
            Bt[0] = pack4(w[0], w[1], w[2],  w[3]);
            Bt[1] = pack4(w[4], w[5], w[6],  w[7]);
            Bt[2] = pack4(w[8], w[9], w[10], w[11]);

            ++t;
            if (t >= gmax) break;
        }
    }

    if (lane < GG) ws[seq] = zcap;   // 4 replicas agree; lanes 0..15 write
}

__global__ __launch_bounds__(512) void reduce_mean_kernel(
    const float* __restrict__ ws, float* __restrict__ out)
{
    __shared__ float sm[8];
    int tid = threadIdx.x;          // 512 threads = 8 waves
    float x = ws[tid] - ws[BB + tid];   // logZ_b - path_b
    x = wave_reduce_sum(x);
    if ((tid & 63) == 0) sm[tid >> 6] = x;
    __syncthreads();
    if (tid < 8) {
        float y = sm[tid];
        y += __shfl_xor(y, 1, 64);
        y += __shfl_xor(y, 2, 64);
        y += __shfl_xor(y, 4, 64);
        if (tid == 0) out[0] = y * (1.0f / 512.0f);
    }
}

extern "C" void kernel_launch(void* const* d_in, const int* in_sizes, int n_in,
                              void* d_out, int out_size, void* d_ws, size_t ws_size,
                              hipStream_t stream) {
    const float* emis    = (const float*)d_in[0];
    const int*   lengths = (const int*)  d_in[1];
    const int*   tags    = (const int*)  d_in[2];
    const float* prior   = (const float*)d_in[3];
    const float* trans   = (const float*)d_in[4];
    const float* finalT  = (const float*)d_in[5];

    float* ws  = (float*)d_ws;     // [0..511] logZ, [512..1023] path score
    float* out = (float*)d_out;

    crf_main_kernel<<<NGRP + BB, 64, 0, stream>>>(emis, lengths, tags, prior,
                                                  trans, finalT, ws);
    reduce_mean_kernel<<<1, 512, 0, stream>>>(ws, out);
}

// Round 5
// 407.963 us; speedup vs baseline: 1.1248x; 1.1248x over previous
//
#include <hip/hip_runtime.h>

// CRF loss: mean over batch of (logZ - path_score).  B=512, T=1024, K=48.
//
// Forward: 16 sequences per wave-pair, 32 blocks x 128 threads.
//   wave 0 (consumer): scaled linear-domain recurrence as 48x48 @ 48x16 MFMA
//     per step: Q' = (expT @ Q) .* expE_t, per-column log-scale c.
//     D-layout == B-layout for v_mfma_f32_16x16x16_bf16, so D feeds the next
//     step's B via per-lane mul + bf16 pack only.
//   wave 1 (producer): streams emissions into a 16-slot x 4KB LDS ring via
//     global_load_lds (no VGPR round-trip). One __syncthreads per 8-step
//     phase, producer one phase ahead -> HBM latency off the critical path.
//     (Round 4 lesson: a VGPR prefetch pipeline got demoted by the RA and
//     serialized ~900cyc HBM latency into every step: 853 cyc/step measured.)
// LDS granule swizzle: granule(seq,kg) = seq*16 + (kg ^ seq) keeps the
// producer's fixed base+16*lane DMA layout AND makes consumer ds_read_b128
// 2-way-conflict-free (2-way is free on gfx950).
// Ragged lengths: capture logZ at t == len-1 (ballot-guarded); per-column
// rescale every 8 steps bounds fp32/bf16 range.
// Path-score blocks (32..543) share the launch and overlap the forward waves.

#define BB    512
#define TT    1024
#define KK    48
#define GG    16
#define NGRP  32
#define NSLOT 16
#define SLOTB 4096
#define PHASE 8

typedef __attribute__((ext_vector_type(4))) short bf16x4;
typedef __attribute__((ext_vector_type(4))) float f32x4;

__device__ __forceinline__ f32x4 mfma16(bf16x4 a, bf16x4 b, f32x4 c) {
#if __has_builtin(__builtin_amdgcn_mfma_f32_16x16x16bf16_1k)
    return __builtin_amdgcn_mfma_f32_16x16x16bf16_1k(a, b, c, 0, 0, 0);
#else
    f32x4 d;
    asm volatile("v_mfma_f32_16x16x16_bf16 %0, %1, %2, %3"
                 : "=v"(d) : "v"(a), "v"(b), "v"(c));
    return d;
#endif
}

__device__ __forceinline__ unsigned pk2(float lo, float hi) {
    return __builtin_amdgcn_perm(__float_as_uint(hi) + 0x8000u,
                                 __float_as_uint(lo) + 0x8000u,
                                 0x07060302u);
}
__device__ __forceinline__ bf16x4 pack4(float a, float b, float c, float d) {
    union { unsigned u[2]; bf16x4 v; } x;
    x.u[0] = pk2(a, b);
    x.u[1] = pk2(c, d);
    return x.v;
}

__device__ __forceinline__ float wave_reduce_sum(float v) {
    #pragma unroll
    for (int off = 32; off > 0; off >>= 1)
        v += __shfl_xor(v, off, 64);
    return v;
}

__device__ __forceinline__ void load_lds16(const float* g, void* l) {
    __builtin_amdgcn_global_load_lds(
        (const __attribute__((address_space(1))) unsigned int*)g,
        (__attribute__((address_space(3))) unsigned int*)l,
        16, 0, 0);
}

__global__ __launch_bounds__(128, 1) void crf_main_kernel(
    const float* __restrict__ emis,    // [B,T,K]
    const int*   __restrict__ lengths, // [B]
    const int*   __restrict__ tags,    // [B,T]
    const float* __restrict__ prior,   // [K]
    const float* __restrict__ trans,   // [K,K] trans[dest][src]
    const float* __restrict__ finalT,  // [K]
    float*       __restrict__ ws)      // [0..511] logZ, [512..1023] path
{
    __shared__ __align__(16) unsigned char ring[NSLOT * SLOTB];   // 64 KB

    const int tid  = threadIdx.x;
    const int wv   = tid >> 6;
    const int lane = tid & 63;

    // ================= path-score blocks =================
    if (blockIdx.x >= NGRP) {
        const int b = blockIdx.x - NGRP;
        int len = lengths[b];
        len = (len < 1) ? 1 : (len > TT ? TT : len);
        const float* eb = emis + (size_t)b * TT * KK;
        const int*   tg = tags + (size_t)b * TT;
        float ps = 0.0f;
        for (int t = tid; t < len; t += 128) {
            int cur = tg[t];
            float ev = eb[(size_t)t * KK + cur];
            float tr = (t == 0) ? prior[cur] : trans[cur * KK + tg[t - 1]];
            ps += ev + tr;
        }
        ps = wave_reduce_sum(ps);
        float* red = (float*)ring;
        if (lane == 0) red[wv] = ps;
        __syncthreads();
        if (tid == 0) ws[BB + b] = red[0] + red[1] + finalT[tg[len - 1]];
        return;
    }

    // ================= forward blocks =================
    const int g = blockIdx.x;

    // gmax computed identically by both waves
    int myLen = lengths[g * GG + (lane & 15)];
    myLen = (myLen < 1) ? 1 : (myLen > TT ? TT : myLen);
    int gmax = myLen;
    #pragma unroll
    for (int off = 32; off > 0; off >>= 1) {
        int o = __shfl_xor(gmax, off, 64);
        gmax = (o > gmax) ? o : gmax;
    }
    const int nsteps = gmax - 1;                 // steps t = 1..nsteps
    const int nphase = (nsteps + PHASE - 1) / PHASE;

    if (wv == 1) {
        // ---------------- producer (DMA) wave ----------------
        // instruction j, lane p -> LDS granule j*64+p; holds seq s = j*4+(p>>4),
        // granule kg = (p&15) ^ s  (floats 4kg..4kg+3 of the row)
        const float* base[4];
        #pragma unroll
        for (int j = 0; j < 4; ++j) {
            int s  = j * 4 + (lane >> 4);
            int kg = (lane & 15) ^ s;
            if (kg >= 12) kg = 0;                // pad granule, never read
            base[j] = emis + ((size_t)(g * GG + s) * TT) * KK + kg * 4;
        }
        for (int k = 0; k < nphase; ++k) {
            int t0 = 1 + k * PHASE;
            #pragma unroll
            for (int s8 = 0; s8 < PHASE; ++s8) {
                int t  = t0 + s8;
                int tc = (t > nsteps) ? nsteps : t;
                unsigned char* lp = &ring[(t & (NSLOT - 1)) * SLOTB];
                #pragma unroll
                for (int j = 0; j < 4; ++j)
                    load_lds16(base[j] + (size_t)tc * KK, lp + j * 1024);
            }
            __syncthreads();                     // drains vmcnt; off crit path
        }
        return;
    }

    // ---------------- consumer (MFMA) wave ----------------
    const int col   = lane & 15;
    const int grp   = lane >> 4;
    const int rbase = grp * 4;
    const int seq   = g * GG + col;
    const int lenn1 = myLen - 1;

    // A tiles: bf16(exp(trans)); A[m][k]: m = mt*16+col, k = kt*16+rbase+j
    bf16x4 A[3][3];
    #pragma unroll
    for (int mt = 0; mt < 3; ++mt) {
        #pragma unroll
        for (int kt = 0; kt < 3; ++kt) {
            float4 tv = *reinterpret_cast<const float4*>(
                trans + (size_t)(mt * 16 + col) * KK + kt * 16 + rbase);
            A[mt][kt] = pack4(__expf(tv.x), __expf(tv.y),
                              __expf(tv.z), __expf(tv.w));
        }
    }

    float expF[12];
    #pragma unroll
    for (int mt = 0; mt < 3; ++mt) {
        float4 fv = *reinterpret_cast<const float4*>(finalT + mt * 16 + rbase);
        expF[mt*4+0] = __expf(fv.x); expF[mt*4+1] = __expf(fv.y);
        expF[mt*4+2] = __expf(fv.z); expF[mt*4+3] = __expf(fv.w);
    }

    const float* ebase = emis + (size_t)seq * TT * KK + rbase;

    // init (t=0): w = exp(E0 + prior - c), c = per-column max
    float w[12];
    float c;
    float zcap = 0.0f;
    {
        float a0[12];
        #pragma unroll
        for (int mt = 0; mt < 3; ++mt) {
            float4 ev = *reinterpret_cast<const float4*>(ebase + mt * 16);
            float4 pv = *reinterpret_cast<const float4*>(prior + mt * 16 + rbase);
            a0[mt*4+0] = ev.x + pv.x;
            a0[mt*4+1] = ev.y + pv.y;
            a0[mt*4+2] = ev.z + pv.z;
            a0[mt*4+3] = ev.w + pv.w;
        }
        float mx = a0[0];
        #pragma unroll
        for (int r = 1; r < 12; ++r) mx = fmaxf(mx, a0[r]);
        mx = fmaxf(mx, __shfl_xor(mx, 16, 64));
        mx = fmaxf(mx, __shfl_xor(mx, 32, 64));
        c = mx;
        #pragma unroll
        for (int r = 0; r < 12; ++r) w[r] = __expf(a0[r] - c);
        if (__ballot(lenn1 == 0)) {
            float S = 0.0f;
            #pragma unroll
            for (int r = 0; r < 12; ++r) S = fmaf(w[r], expF[r], S);
            S += __shfl_xor(S, 16, 64);
            S += __shfl_xor(S, 32, 64);
            if (lenn1 == 0) zcap = c + __logf(S);
        }
    }

    bf16x4 Bt[3];
    Bt[0] = pack4(w[0], w[1], w[2],  w[3]);
    Bt[1] = pack4(w[4], w[5], w[6],  w[7]);
    Bt[2] = pack4(w[8], w[9], w[10], w[11]);

    // LDS byte offsets for this lane's three 16B granules (kg = mt*4+grp)
    int loff[3];
    #pragma unroll
    for (int mt = 0; mt < 3; ++mt)
        loff[mt] = col * 256 + (((mt * 4 + grp) ^ col) << 4);

    const f32x4 zero4 = {0.f, 0.f, 0.f, 0.f};
    int t = 1;
    for (int k = 0; k < nphase; ++k) {
        __syncthreads();                         // phase k data is ready
        #pragma unroll
        for (int s8 = 0; s8 < PHASE; ++s8) {
            if (t > nsteps) break;
            const unsigned char* sp = &ring[(t & (NSLOT - 1)) * SLOTB];
            float4 E0 = *reinterpret_cast<const float4*>(sp + loff[0]);
            float4 E1 = *reinterpret_cast<const float4*>(sp + loff[1]);
            float4 E2 = *reinterpret_cast<const float4*>(sp + loff[2]);

            // Q' = expT @ Q : 9 MFMAs, 3 independent acc chains
            f32x4 D0 = mfma16(A[0][0], Bt[0], zero4);
            f32x4 D1 = mfma16(A[1][0], Bt[0], zero4);
            f32x4 D2 = mfma16(A[2][0], Bt[0], zero4);
            D0 = mfma16(A[0][1], Bt[1], D0);
            D1 = mfma16(A[1][1], Bt[1], D1);
            D2 = mfma16(A[2][1], Bt[1], D2);
            D0 = mfma16(A[0][2], Bt[2], D0);
            D1 = mfma16(A[1][2], Bt[2], D1);
            D2 = mfma16(A[2][2], Bt[2], D2);

            // apply emissions (fp32); D-layout == B-layout
            w[0]  = D0.x * __expf(E0.x);
            w[1]  = D0.y * __expf(E0.y);
            w[2]  = D0.z * __expf(E0.z);
            w[3]  = D0.w * __expf(E0.w);
            w[4]  = D1.x * __expf(E1.x);
            w[5]  = D1.y * __expf(E1.y);
            w[6]  = D1.z * __expf(E1.z);
            w[7]  = D1.w * __expf(E1.w);
            w[8]  = D2.x * __expf(E2.x);
            w[9]  = D2.y * __expf(E2.y);
            w[10] = D2.z * __expf(E2.z);
            w[11] = D2.w * __expf(E2.w);

            // per-column rescale every 8 steps
            if ((t & 7) == 0) {
                float mx = w[0];
                #pragma unroll
                for (int r = 1; r < 12; ++r) mx = fmaxf(mx, w[r]);
                mx = fmaxf(mx, __shfl_xor(mx, 16, 64));
                mx = fmaxf(mx, __shfl_xor(mx, 32, 64));
                c += __logf(mx);
                float rm = __builtin_amdgcn_rcpf(mx);
                #pragma unroll
                for (int r = 0; r < 12; ++r) w[r] *= rm;
            }

            // capture finished columns (rare; ballot-guarded)
            if (__ballot(t == lenn1)) {
                float S = 0.0f;
                #pragma unroll
                for (int r = 0; r < 12; ++r) S = fmaf(w[r], expF[r], S);
                S += __shfl_xor(S, 16, 64);
                S += __shfl_xor(S, 32, 64);
                if (t == lenn1) zcap = c + __logf(S);
            }

            // repack state for next step's B operand
            Bt[0] = pack4(w[0], w[1], w[2],  w[3]);
            Bt[1] = pack4(w[4], w[5], w[6],  w[7]);
            Bt[2] = pack4(w[8], w[9], w[10], w[11]);

            ++t;
        }
    }

    if (lane < GG) ws[seq] = zcap;   // 4 replicas agree; lanes 0..15 write
}

__global__ __launch_bounds__(512) void reduce_mean_kernel(
    const float* __restrict__ ws, float* __restrict__ out)
{
    __shared__ float sm[8];
    int tid = threadIdx.x;          // 512 threads = 8 waves
    float x = ws[tid] - ws[BB + tid];   // logZ_b - path_b
    x = wave_reduce_sum(x);
    if ((tid & 63) == 0) sm[tid >> 6] = x;
    __syncthreads();
    if (tid < 8) {
        float y = sm[tid];
        y += __shfl_xor(y, 1, 64);
        y += __shfl_xor(y, 2, 64);
        y += __shfl_xor(y, 4, 64);
        if (tid == 0) out[0] = y * (1.0f / 512.0f);
    }
}

extern "C" void kernel_launch(void* const* d_in, const int* in_sizes, int n_in,
                              void* d_out, int out_size, void* d_ws, size_t ws_size,
                              hipStream_t stream) {
    const float* emis    = (const float*)d_in[0];
    const int*   lengths = (const int*)  d_in[1];
    const int*   tags    = (const int*)  d_in[2];
    const float* prior   = (const float*)d_in[3];
    const float* trans   = (const float*)d_in[4];
    const float* finalT  = (const float*)d_in[5];

    float* ws  = (float*)d_ws;     // [0..511] logZ, [512..1023] path score
    float* out = (float*)d_out;

    crf_main_kernel<<<NGRP + BB, 128, 0, stream>>>(emis, lengths, tags, prior,
                                                   trans, finalT, ws);
    reduce_mean_kernel<<<1, 512, 0, stream>>>(ws, out);
}

// Round 6
// 341.219 us; speedup vs baseline: 1.3448x; 1.1956x over previous
//
#include <hip/hip_runtime.h>

// CRF loss: mean over batch of (logZ - path_score).  B=512, T=1024, K=48.
//
// Forward: 16 sequences per block, 32 blocks x 320 threads (5 waves).
//   wave 0 (consumer): scaled linear-domain recurrence as 48x48 @ 48x16 MFMA
//     per step: Q' = (expT @ Q) .* expE_t, per-column log-scale c.
//     D-layout == B-layout for v_mfma_f32_16x16x16_bf16, so D feeds the next
//     step's B via per-lane mul + bf16 pack only.
//   waves 1..4 (producers): stream emissions into a 16-slot x 4KB LDS ring
//     via global_load_lds. Round-5 lesson: ONE producer wave bottlenecked at
//     ~5.9 B/cyc (per-wave LDS-DMA outstanding limit ~5 at ~900cyc HBM
//     latency -> 5600 cyc/phase). Four waves x 8 loads each restore
//     phase-drain ~1100 cyc, under the consumer's ~1300.
//   One __syncthreads per 8-step phase; producers run one phase ahead.
// Consumer phases run full-width (no data-dependent break): steps past
// nsteps read clamped data and are harmless; this lets the scheduler batch
// the phase's 24 ds_read_b128 right after the barrier.
// LDS granule swizzle: granule(seq,kg) = seq*16 + (kg ^ seq) keeps the
// producer's fixed base+16*lane DMA layout AND makes consumer ds_read_b128
// 2-way-conflict-free (2-way is free on gfx950).
// Ragged lengths: capture logZ at t == len-1 (ballot-guarded); per-column
// rescale every 8 steps bounds fp32/bf16 range.
// Path-score blocks (32..543) share the launch and overlap the forward waves.

#define BB    512
#define TT    1024
#define KK    48
#define GG    16
#define NGRP  32
#define NSLOT 16
#define SLOTB 4096
#define PHASE 8
#define NPROD 4
#define BLKT  (64 * (1 + NPROD))

typedef __attribute__((ext_vector_type(4))) short bf16x4;
typedef __attribute__((ext_vector_type(4))) float f32x4;

__device__ __forceinline__ f32x4 mfma16(bf16x4 a, bf16x4 b, f32x4 c) {
#if __has_builtin(__builtin_amdgcn_mfma_f32_16x16x16bf16_1k)
    return __builtin_amdgcn_mfma_f32_16x16x16bf16_1k(a, b, c, 0, 0, 0);
#else
    f32x4 d;
    asm volatile("v_mfma_f32_16x16x16_bf16 %0, %1, %2, %3"
                 : "=v"(d) : "v"(a), "v"(b), "v"(c));
    return d;
#endif
}

__device__ __forceinline__ unsigned pk2(float lo, float hi) {
    return __builtin_amdgcn_perm(__float_as_uint(hi) + 0x8000u,
                                 __float_as_uint(lo) + 0x8000u,
                                 0x07060302u);
}
__device__ __forceinline__ bf16x4 pack4(float a, float b, float c, float d) {
    union { unsigned u[2]; bf16x4 v; } x;
    x.u[0] = pk2(a, b);
    x.u[1] = pk2(c, d);
    return x.v;
}

__device__ __forceinline__ float wave_reduce_sum(float v) {
    #pragma unroll
    for (int off = 32; off > 0; off >>= 1)
        v += __shfl_xor(v, off, 64);
    return v;
}

__device__ __forceinline__ void load_lds16(const float* g, void* l) {
    __builtin_amdgcn_global_load_lds(
        (const __attribute__((address_space(1))) unsigned int*)g,
        (__attribute__((address_space(3))) unsigned int*)l,
        16, 0, 0);
}

__global__ __launch_bounds__(BLKT, 1) void crf_main_kernel(
    const float* __restrict__ emis,    // [B,T,K]
    const int*   __restrict__ lengths, // [B]
    const int*   __restrict__ tags,    // [B,T]
    const float* __restrict__ prior,   // [K]
    const float* __restrict__ trans,   // [K,K] trans[dest][src]
    const float* __restrict__ finalT,  // [K]
    float*       __restrict__ ws)      // [0..511] logZ, [512..1023] path
{
    __shared__ __align__(16) unsigned char ring[NSLOT * SLOTB];   // 64 KB

    const int tid  = threadIdx.x;
    const int wv   = tid >> 6;
    const int lane = tid & 63;

    // ================= path-score blocks =================
    if (blockIdx.x >= NGRP) {
        const int b = blockIdx.x - NGRP;
        int len = lengths[b];
        len = (len < 1) ? 1 : (len > TT ? TT : len);
        const float* eb = emis + (size_t)b * TT * KK;
        const int*   tg = tags + (size_t)b * TT;
        float ps = 0.0f;
        for (int t = tid; t < len; t += BLKT) {
            int cur = tg[t];
            float ev = eb[(size_t)t * KK + cur];
            float tr = (t == 0) ? prior[cur] : trans[cur * KK + tg[t - 1]];
            ps += ev + tr;
        }
        ps = wave_reduce_sum(ps);
        float* red = (float*)ring;
        if (lane == 0) red[wv] = ps;
        __syncthreads();
        if (tid == 0) {
            float s = red[0];
            #pragma unroll
            for (int j = 1; j <= NPROD; ++j) s += red[j];
            ws[BB + b] = s + finalT[tg[len - 1]];
        }
        return;
    }

    // ================= forward blocks =================
    const int g = blockIdx.x;

    // gmax computed identically by every wave
    int myLen = lengths[g * GG + (lane & 15)];
    myLen = (myLen < 1) ? 1 : (myLen > TT ? TT : myLen);
    int gmax = myLen;
    #pragma unroll
    for (int off = 32; off > 0; off >>= 1) {
        int o = __shfl_xor(gmax, off, 64);
        gmax = (o > gmax) ? o : gmax;
    }
    const int nsteps = gmax - 1;                 // steps t = 1..nsteps
    const int nphase = (nsteps + PHASE - 1) / PHASE;

    if (wv >= 1) {
        // ---------------- producer (DMA) waves ----------------
        // wave wv handles step-slots s8 = (wv-1) and (wv-1)+4 of each phase.
        // instruction j, lane p -> granule j*64+p; seq s = j*4+(p>>4),
        // granule kg = (p&15) ^ s  (floats 4kg..4kg+3 of the row)
        const float* base[4];
        #pragma unroll
        for (int j = 0; j < 4; ++j) {
            int s  = j * 4 + (lane >> 4);
            int kg = (lane & 15) ^ s;
            if (kg >= 12) kg = 0;                // pad granule, never read
            base[j] = emis + ((size_t)(g * GG + s) * TT) * KK + kg * 4;
        }
        for (int k = 0; k < nphase; ++k) {
            int t0 = 1 + k * PHASE + (wv - 1);
            #pragma unroll
            for (int h = 0; h < 2; ++h) {
                int t  = t0 + 4 * h;
                int tc = (t > nsteps) ? nsteps : t;
                unsigned char* lp = &ring[(t & (NSLOT - 1)) * SLOTB];
                #pragma unroll
                for (int j = 0; j < 4; ++j)
                    load_lds16(base[j] + (size_t)tc * KK, lp + j * 1024);
            }
            __syncthreads();                 // drain (~1100cyc) overlaps C
        }
        return;
    }

    // ---------------- consumer (MFMA) wave ----------------
    const int col   = lane & 15;
    const int grp   = lane >> 4;
    const int rbase = grp * 4;
    const int seq   = g * GG + col;
    const int lenn1 = myLen - 1;

    // A tiles: bf16(exp(trans)); A[m][k]: m = mt*16+col, k = kt*16+rbase+j
    bf16x4 A[3][3];
    #pragma unroll
    for (int mt = 0; mt < 3; ++mt) {
        #pragma unroll
        for (int kt = 0; kt < 3; ++kt) {
            float4 tv = *reinterpret_cast<const float4*>(
                trans + (size_t)(mt * 16 + col) * KK + kt * 16 + rbase);
            A[mt][kt] = pack4(__expf(tv.x), __expf(tv.y),
                              __expf(tv.z), __expf(tv.w));
        }
    }

    float expF[12];
    #pragma unroll
    for (int mt = 0; mt < 3; ++mt) {
        float4 fv = *reinterpret_cast<const float4*>(finalT + mt * 16 + rbase);
        expF[mt*4+0] = __expf(fv.x); expF[mt*4+1] = __expf(fv.y);
        expF[mt*4+2] = __expf(fv.z); expF[mt*4+3] = __expf(fv.w);
    }

    const float* ebase = emis + (size_t)seq * TT * KK + rbase;

    // init (t=0): w = exp(E0 + prior - c), c = per-column max
    float w[12];
    float c;
    float zcap = 0.0f;
    {
        float a0[12];
        #pragma unroll
        for (int mt = 0; mt < 3; ++mt) {
            float4 ev = *reinterpret_cast<const float4*>(ebase + mt * 16);
            float4 pv = *reinterpret_cast<const float4*>(prior + mt * 16 + rbase);
            a0[mt*4+0] = ev.x + pv.x;
            a0[mt*4+1] = ev.y + pv.y;
            a0[mt*4+2] = ev.z + pv.z;
            a0[mt*4+3] = ev.w + pv.w;
        }
        float mx = a0[0];
        #pragma unroll
        for (int r = 1; r < 12; ++r) mx = fmaxf(mx, a0[r]);
        mx = fmaxf(mx, __shfl_xor(mx, 16, 64));
        mx = fmaxf(mx, __shfl_xor(mx, 32, 64));
        c = mx;
        #pragma unroll
        for (int r = 0; r < 12; ++r) w[r] = __expf(a0[r] - c);
        if (__ballot(lenn1 == 0)) {
            float S = 0.0f;
            #pragma unroll
            for (int r = 0; r < 12; ++r) S = fmaf(w[r], expF[r], S);
            S += __shfl_xor(S, 16, 64);
            S += __shfl_xor(S, 32, 64);
            if (lenn1 == 0) zcap = c + __logf(S);
        }
    }

    bf16x4 Bt[3];
    Bt[0] = pack4(w[0], w[1], w[2],  w[3]);
    Bt[1] = pack4(w[4], w[5], w[6],  w[7]);
    Bt[2] = pack4(w[8], w[9], w[10], w[11]);

    // LDS byte offsets for this lane's three 16B granules (kg = mt*4+grp)
    int loff[3];
    #pragma unroll
    for (int mt = 0; mt < 3; ++mt)
        loff[mt] = col * 256 + (((mt * 4 + grp) ^ col) << 4);

    const f32x4 zero4 = {0.f, 0.f, 0.f, 0.f};
    for (int k = 0; k < nphase; ++k) {
        __syncthreads();                         // phase k data is ready
        #pragma unroll
        for (int s8 = 0; s8 < PHASE; ++s8) {
            const int t = 1 + k * PHASE + s8;    // may exceed nsteps: harmless
            const unsigned char* sp = &ring[(t & (NSLOT - 1)) * SLOTB];
            float4 E0 = *reinterpret_cast<const float4*>(sp + loff[0]);
            float4 E1 = *reinterpret_cast<const float4*>(sp + loff[1]);
            float4 E2 = *reinterpret_cast<const float4*>(sp + loff[2]);

            // Q' = expT @ Q : 9 MFMAs, 3 independent acc chains
            f32x4 D0 = mfma16(A[0][0], Bt[0], zero4);
            f32x4 D1 = mfma16(A[1][0], Bt[0], zero4);
            f32x4 D2 = mfma16(A[2][0], Bt[0], zero4);
            D0 = mfma16(A[0][1], Bt[1], D0);
            D1 = mfma16(A[1][1], Bt[1], D1);
            D2 = mfma16(A[2][1], Bt[1], D2);
            D0 = mfma16(A[0][2], Bt[2], D0);
            D1 = mfma16(A[1][2], Bt[2], D1);
            D2 = mfma16(A[2][2], Bt[2], D2);

            // apply emissions (fp32); D-layout == B-layout
            w[0]  = D0.x * __expf(E0.x);
            w[1]  = D0.y * __expf(E0.y);
            w[2]  = D0.z * __expf(E0.z);
            w[3]  = D0.w * __expf(E0.w);
            w[4]  = D1.x * __expf(E1.x);
            w[5]  = D1.y * __expf(E1.y);
            w[6]  = D1.z * __expf(E1.z);
            w[7]  = D1.w * __expf(E1.w);
            w[8]  = D2.x * __expf(E2.x);
            w[9]  = D2.y * __expf(E2.y);
            w[10] = D2.z * __expf(E2.z);
            w[11] = D2.w * __expf(E2.w);

            // per-column rescale: (t&7)==0 constant-folds to s8==7
            if ((t & 7) == 0) {
                float mx = w[0];
                #pragma unroll
                for (int r = 1; r < 12; ++r) mx = fmaxf(mx, w[r]);
                mx = fmaxf(mx, __shfl_xor(mx, 16, 64));
                mx = fmaxf(mx, __shfl_xor(mx, 32, 64));
                c += __logf(mx);
                float rm = __builtin_amdgcn_rcpf(mx);
                #pragma unroll
                for (int r = 0; r < 12; ++r) w[r] *= rm;
            }

            // capture finished columns (rare; ballot-guarded)
            if (__ballot(t == lenn1)) {
                float S = 0.0f;
                #pragma unroll
                for (int r = 0; r < 12; ++r) S = fmaf(w[r], expF[r], S);
                S += __shfl_xor(S, 16, 64);
                S += __shfl_xor(S, 32, 64);
                if (t == lenn1) zcap = c + __logf(S);
            }

            // repack state for next step's B operand
            Bt[0] = pack4(w[0], w[1], w[2],  w[3]);
            Bt[1] = pack4(w[4], w[5], w[6],  w[7]);
            Bt[2] = pack4(w[8], w[9], w[10], w[11]);
        }
    }

    if (lane < GG) ws[seq] = zcap;   // 4 replicas agree; lanes 0..15 write
}

__global__ __launch_bounds__(512) void reduce_mean_kernel(
    const float* __restrict__ ws, float* __restrict__ out)
{
    __shared__ float sm[8];
    int tid = threadIdx.x;          // 512 threads = 8 waves
    float x = ws[tid] - ws[BB + tid];   // logZ_b - path_b
    x = wave_reduce_sum(x);
    if ((tid & 63) == 0) sm[tid >> 6] = x;
    __syncthreads();
    if (tid < 8) {
        float y = sm[tid];
        y += __shfl_xor(y, 1, 64);
        y += __shfl_xor(y, 2, 64);
        y += __shfl_xor(y, 4, 64);
        if (tid == 0) out[0] = y * (1.0f / 512.0f);
    }
}

extern "C" void kernel_launch(void* const* d_in, const int* in_sizes, int n_in,
                              void* d_out, int out_size, void* d_ws, size_t ws_size,
                              hipStream_t stream) {
    const float* emis    = (const float*)d_in[0];
    const int*   lengths = (const int*)  d_in[1];
    const int*   tags    = (const int*)  d_in[2];
    const float* prior   = (const float*)d_in[3];
    const float* trans   = (const float*)d_in[4];
    const float* finalT  = (const float*)d_in[5];

    float* ws  = (float*)d_ws;     // [0..511] logZ, [512..1023] path score
    float* out = (float*)d_out;

    crf_main_kernel<<<NGRP + BB, BLKT, 0, stream>>>(emis, lengths, tags, prior,
                                                    trans, finalT, ws);
    reduce_mean_kernel<<<1, 512, 0, stream>>>(ws, out);
}

// Round 7
// 331.632 us; speedup vs baseline: 1.3837x; 1.0289x over previous
//
#include <hip/hip_runtime.h>

// CRF loss: mean over batch of (logZ - path_score).  B=512, T=1024, K=48.
//
// Forward: 16 sequences per block, 32 blocks x 256 threads (4 waves, one per
// SIMD -- consumer never shares issue slots with producers).
//   wave 0 (consumer): scaled linear-domain recurrence as 48x48 @ 48x16 MFMA
//     per step: Q' = (expT @ Q) .* expE_t, per-column log-scale c.
//     D-layout == B-layout for v_mfma_f32_16x16x16_bf16, so D feeds the next
//     step's B via per-lane mul + bf16 pack only. Emissions arrive from LDS
//     ALREADY EXPONENTIATED (round-6 lesson: 12 quarter-rate v_exp = 96
//     issue-cyc/step made the consumer the ~540 cyc/step bottleneck).
//   waves 1..3 (producers): global_load_dwordx4 -> VGPR (deep vmcnt queue,
//     avoids the ~5-deep LDS-DMA queue of global_load_lds seen in r5/r6),
//     v_exp on idle VALU, ds_write_b128 into a 16-slot x 3KB LDS ring.
// Sync: NO __syncthreads in the pipeline (its vmcnt(0) drain would expose
// full HBM latency every phase -- the m97 wall). LDS flag handshake instead:
// per-producer phase counters (single-writer) + consumer progress counter.
// DS ops are in-order per wave; __threadfence_block gives release ordering.
// Producer k gates on cons >= k-1 (slot reuse, 16 slots = 2 phases);
// consumer k gates on all three prod counters >= k+1. No summed counter:
// two producers running ahead must not mask a lagging third.
// Slot layout: granule idx = seq*12+kg at byte idx*16 (packed 192x16B =
// 3072B). Conflict-free (8-pass floor) for both b128 writes and reads.
// Ragged lengths: capture logZ at t == len-1 (ballot-guarded); per-column
// rescale every 8 steps bounds fp32/bf16 range.
// Path-score blocks (32..543) share the launch and overlap the forward waves.

#define BB    512
#define TT    1024
#define KK    48
#define GG    16
#define NGRP  32
#define NSLOT 16
#define SLOTB (KK * GG * 4)     // 3072 B per time-step slot
#define PHASE 8
#define NPROD 3
#define BLKT  256

typedef __attribute__((ext_vector_type(4))) short bf16x4;
typedef __attribute__((ext_vector_type(4))) float f32x4;

__device__ __forceinline__ f32x4 mfma16(bf16x4 a, bf16x4 b, f32x4 c) {
#if __has_builtin(__builtin_amdgcn_mfma_f32_16x16x16bf16_1k)
    return __builtin_amdgcn_mfma_f32_16x16x16bf16_1k(a, b, c, 0, 0, 0);
#else
    f32x4 d;
    asm volatile("v_mfma_f32_16x16x16_bf16 %0, %1, %2, %3"
                 : "=v"(d) : "v"(a), "v"(b), "v"(c));
    return d;
#endif
}

#if __has_builtin(__builtin_amdgcn_cvt_pk_bf16_f32)
typedef __attribute__((ext_vector_type(2))) __bf16 bf16x2_v;
__device__ __forceinline__ unsigned pk2(float lo, float hi) {
    union { bf16x2_v v; unsigned u; } x;
    x.v = __builtin_amdgcn_cvt_pk_bf16_f32(lo, hi);
    return x.u;
}
#else
__device__ __forceinline__ unsigned pk2(float lo, float hi) {
    return __builtin_amdgcn_perm(__float_as_uint(hi) + 0x8000u,
                                 __float_as_uint(lo) + 0x8000u,
                                 0x07060302u);
}
#endif
__device__ __forceinline__ bf16x4 pack4(float a, float b, float c, float d) {
    union { unsigned u[2]; bf16x4 v; } x;
    x.u[0] = pk2(a, b);
    x.u[1] = pk2(c, d);
    return x.v;
}

__device__ __forceinline__ float wave_reduce_sum(float v) {
    #pragma unroll
    for (int off = 32; off > 0; off >>= 1)
        v += __shfl_xor(v, off, 64);
    return v;
}

__global__ __launch_bounds__(BLKT, 1) void crf_main_kernel(
    const float* __restrict__ emis,    // [B,T,K]
    const int*   __restrict__ lengths, // [B]
    const int*   __restrict__ tags,    // [B,T]
    const float* __restrict__ prior,   // [K]
    const float* __restrict__ trans,   // [K,K] trans[dest][src]
    const float* __restrict__ finalT,  // [K]
    float*       __restrict__ ws)      // [0..511] logZ, [512..1023] path
{
    __shared__ __align__(16) unsigned char ring[NSLOT * SLOTB];  // 48 KB
    __shared__ int prodCnt[NPROD];
    __shared__ int consCnt;

    const int tid  = threadIdx.x;
    const int wv   = tid >> 6;
    const int lane = tid & 63;

    // ================= path-score blocks =================
    if (blockIdx.x >= NGRP) {
        const int b = blockIdx.x - NGRP;
        int len = lengths[b];
        len = (len < 1) ? 1 : (len > TT ? TT : len);
        const float* eb = emis + (size_t)b * TT * KK;
        const int*   tg = tags + (size_t)b * TT;
        float ps = 0.0f;
        for (int t = tid; t < len; t += BLKT) {
            int cur = tg[t];
            float ev = eb[(size_t)t * KK + cur];
            float tr = (t == 0) ? prior[cur] : trans[cur * KK + tg[t - 1]];
            ps += ev + tr;
        }
        ps = wave_reduce_sum(ps);
        float* red = (float*)ring;
        if (lane == 0) red[wv] = ps;
        __syncthreads();
        if (tid == 0)
            ws[BB + b] = red[0] + red[1] + red[2] + red[3] + finalT[tg[len - 1]];
        return;
    }

    // ================= forward blocks =================
    const int g = blockIdx.x;

    if (tid == 0) {
        prodCnt[0] = 0; prodCnt[1] = 0; prodCnt[2] = 0; consCnt = 0;
    }
    __syncthreads();   // one-time flag init; drain cost paid once

    // gmax computed identically by every wave
    int myLen = lengths[g * GG + (lane & 15)];
    myLen = (myLen < 1) ? 1 : (myLen > TT ? TT : myLen);
    int gmax = myLen;
    #pragma unroll
    for (int off = 32; off > 0; off >>= 1) {
        int o = __shfl_xor(gmax, off, 64);
        gmax = (o > gmax) ? o : gmax;
    }
    const int nsteps = gmax - 1;                 // steps t = 1..nsteps
    const int nphase = (nsteps + PHASE - 1) / PHASE;

    if (wv >= 1) {
        // ---------------- producer waves (1..3) ----------------
        // granule idx = lane + 64j (j=0..2) per slot; seq = idx/12, kg = idx%12
        size_t go[3]; int lo16[3];
        #pragma unroll
        for (int j = 0; j < 3; ++j) {
            int idx = lane + 64 * j;
            int s   = idx / 12;
            int kg  = idx - s * 12;
            go[j]   = (size_t)(g * GG + s) * (TT * KK) + kg * 4;
            lo16[j] = idx * 16;
        }
        const int sA = wv - 1;       // slots sA, sA+3, sA+6 (skip if >=8)
        float4 L[9];

#define PLOAD(KP)                                                          \
        {                                                                  \
            _Pragma("unroll")                                              \
            for (int h = 0; h < 3; ++h) {                                  \
                int s = sA + 3 * h;                                        \
                if (s < PHASE) {                                           \
                    int t  = 1 + (KP) * PHASE + s;                         \
                    int tc = (t > nsteps) ? nsteps : t;                    \
                    _Pragma("unroll")                                      \
                    for (int j = 0; j < 3; ++j)                            \
                        L[h*3+j] = *reinterpret_cast<const float4*>(       \
                            emis + go[j] + (size_t)tc * KK);               \
                }                                                          \
            }                                                              \
        }

        PLOAD(0);
        volatile int* vc = &consCnt;
        for (int k = 0; k < nphase; ++k) {
            while (*vc < k - 1) __builtin_amdgcn_s_sleep(1);  // slot reuse gate
            asm volatile("" ::: "memory");
            #pragma unroll
            for (int h = 0; h < 3; ++h) {
                int s = sA + 3 * h;
                if (s < PHASE) {
                    int t = 1 + k * PHASE + s;
                    unsigned char* bp = &ring[(t & (NSLOT - 1)) * SLOTB];
                    #pragma unroll
                    for (int j = 0; j < 3; ++j) {
                        float4 l = L[h*3+j];
                        float4 e;
                        e.x = __expf(l.x); e.y = __expf(l.y);
                        e.z = __expf(l.z); e.w = __expf(l.w);
                        *reinterpret_cast<float4*>(bp + lo16[j]) = e;
                    }
                }
            }
            __threadfence_block();                 // release: writes -> flag
            if (lane == 0) *(volatile int*)&prodCnt[sA] = k + 1;
            PLOAD(k + 1);                          // next phase, in flight
        }
#undef PLOAD
        return;
    }

    // ---------------- consumer (MFMA) wave ----------------
    const int col   = lane & 15;
    const int grp   = lane >> 4;
    const int rbase = grp * 4;
    const int seq   = g * GG + col;
    const int lenn1 = myLen - 1;

    // A tiles: bf16(exp(trans)); A[m][k]: m = mt*16+col, k = kt*16+rbase+j
    bf16x4 A[3][3];
    #pragma unroll
    for (int mt = 0; mt < 3; ++mt) {
        #pragma unroll
        for (int kt = 0; kt < 3; ++kt) {
            float4 tv = *reinterpret_cast<const float4*>(
                trans + (size_t)(mt * 16 + col) * KK + kt * 16 + rbase);
            A[mt][kt] = pack4(__expf(tv.x), __expf(tv.y),
                              __expf(tv.z), __expf(tv.w));
        }
    }

    float expF[12];
    #pragma unroll
    for (int mt = 0; mt < 3; ++mt) {
        float4 fv = *reinterpret_cast<const float4*>(finalT + mt * 16 + rbase);
        expF[mt*4+0] = __expf(fv.x); expF[mt*4+1] = __expf(fv.y);
        expF[mt*4+2] = __expf(fv.z); expF[mt*4+3] = __expf(fv.w);
    }

    const float* ebase = emis + (size_t)seq * TT * KK + rbase;

    // init (t=0): w = exp(E0 + prior - c), c = per-column max
    float w[12];
    float c;
    float zcap = 0.0f;
    {
        float a0[12];
        #pragma unroll
        for (int mt = 0; mt < 3; ++mt) {
            float4 ev = *reinterpret_cast<const float4*>(ebase + mt * 16);
            float4 pv = *reinterpret_cast<const float4*>(prior + mt * 16 + rbase);
            a0[mt*4+0] = ev.x + pv.x;
            a0[mt*4+1] = ev.y + pv.y;
            a0[mt*4+2] = ev.z + pv.z;
            a0[mt*4+3] = ev.w + pv.w;
        }
        float mx = a0[0];
        #pragma unroll
        for (int r = 1; r < 12; ++r) mx = fmaxf(mx, a0[r]);
        mx = fmaxf(mx, __shfl_xor(mx, 16, 64));
        mx = fmaxf(mx, __shfl_xor(mx, 32, 64));
        c = mx;
        #pragma unroll
        for (int r = 0; r < 12; ++r) w[r] = __expf(a0[r] - c);
        if (__ballot(lenn1 == 0)) {
            float S = 0.0f;
            #pragma unroll
            for (int r = 0; r < 12; ++r) S = fmaf(w[r], expF[r], S);
            S += __shfl_xor(S, 16, 64);
            S += __shfl_xor(S, 32, 64);
            if (lenn1 == 0) zcap = c + __logf(S);
        }
    }

    bf16x4 Bt[3];
    Bt[0] = pack4(w[0], w[1], w[2],  w[3]);
    Bt[1] = pack4(w[4], w[5], w[6],  w[7]);
    Bt[2] = pack4(w[8], w[9], w[10], w[11]);

    const int foff = col * 48 + grp * 4;   // float offset of granule (col,grp)
    const f32x4 zero4 = {0.f, 0.f, 0.f, 0.f};
    volatile int* vp = prodCnt;

    for (int k = 0; k < nphase; ++k) {
        while (vp[0] < k + 1 || vp[1] < k + 1 || vp[2] < k + 1)
            __builtin_amdgcn_s_sleep(1);           // phase-k data ready
        asm volatile("" ::: "memory");
        #pragma unroll
        for (int s8 = 0; s8 < PHASE; ++s8) {
            const int t = 1 + k * PHASE + s8;      // may exceed nsteps: harmless
            const float* sp = reinterpret_cast<const float*>(
                &ring[(t & (NSLOT - 1)) * SLOTB]) + foff;
            float4 X0 = *reinterpret_cast<const float4*>(sp);
            float4 X1 = *reinterpret_cast<const float4*>(sp + 16);
            float4 X2 = *reinterpret_cast<const float4*>(sp + 32);

            // Q' = expT @ Q : 9 MFMAs, 3 independent acc chains
            f32x4 D0 = mfma16(A[0][0], Bt[0], zero4);
            f32x4 D1 = mfma16(A[1][0], Bt[0], zero4);
            f32x4 D2 = mfma16(A[2][0], Bt[0], zero4);
            D0 = mfma16(A[0][1], Bt[1], D0);
            D1 = mfma16(A[1][1], Bt[1], D1);
            D2 = mfma16(A[2][1], Bt[1], D2);
            D0 = mfma16(A[0][2], Bt[2], D0);
            D1 = mfma16(A[1][2], Bt[2], D1);
            D2 = mfma16(A[2][2], Bt[2], D2);

            // emissions pre-exponentiated by producers: plain mul
            w[0]  = D0.x * X0.x;  w[1]  = D0.y * X0.y;
            w[2]  = D0.z * X0.z;  w[3]  = D0.w * X0.w;
            w[4]  = D1.x * X1.x;  w[5]  = D1.y * X1.y;
            w[6]  = D1.z * X1.z;  w[7]  = D1.w * X1.w;
            w[8]  = D2.x * X2.x;  w[9]  = D2.y * X2.y;
            w[10] = D2.z * X2.z;  w[11] = D2.w * X2.w;

            // per-column rescale: (t&7)==0 constant-folds to s8==7
            if ((t & 7) == 0) {
                float mx = w[0];
                #pragma unroll
                for (int r = 1; r < 12; ++r) mx = fmaxf(mx, w[r]);
                mx = fmaxf(mx, __shfl_xor(mx, 16, 64));
                mx = fmaxf(mx, __shfl_xor(mx, 32, 64));
                c += __logf(mx);
                float rm = __builtin_amdgcn_rcpf(mx);
                #pragma unroll
                for (int r = 0; r < 12; ++r) w[r] *= rm;
            }

            // capture finished columns (rare; ballot-guarded)
            if (__ballot(t == lenn1)) {
                float S = 0.0f;
                #pragma unroll
                for (int r = 0; r < 12; ++r) S = fmaf(w[r], expF[r], S);
                S += __shfl_xor(S, 16, 64);
                S += __shfl_xor(S, 32, 64);
                if (t == lenn1) zcap = c + __logf(S);
            }

            // repack state for next step's B operand
            Bt[0] = pack4(w[0], w[1], w[2],  w[3]);
            Bt[1] = pack4(w[4], w[5], w[6],  w[7]);
            Bt[2] = pack4(w[8], w[9], w[10], w[11]);
        }
        __threadfence_block();                    // reads done -> progress flag
        asm volatile("" ::: "memory");
        if (lane == 0) *(volatile int*)&consCnt = k + 1;
    }

    if (lane < GG) ws[seq] = zcap;   // 4 replicas agree; lanes 0..15 write
}

__global__ __launch_bounds__(512) void reduce_mean_kernel(
    const float* __restrict__ ws, float* __restrict__ out)
{
    __shared__ float sm[8];
    int tid = threadIdx.x;          // 512 threads = 8 waves
    float x = ws[tid] - ws[BB + tid];   // logZ_b - path_b
    x = wave_reduce_sum(x);
    if ((tid & 63) == 0) sm[tid >> 6] = x;
    __syncthreads();
    if (tid < 8) {
        float y = sm[tid];
        y += __shfl_xor(y, 1, 64);
        y += __shfl_xor(y, 2, 64);
        y += __shfl_xor(y, 4, 64);
        if (tid == 0) out[0] = y * (1.0f / 512.0f);
    }
}

extern "C" void kernel_launch(void* const* d_in, const int* in_sizes, int n_in,
                              void* d_out, int out_size, void* d_ws, size_t ws_size,
                              hipStream_t stream) {
    const float* emis    = (const float*)d_in[0];
    const int*   lengths = (const int*)  d_in[1];
    const int*   tags    = (const int*)  d_in[2];
    const float* prior   = (const float*)d_in[3];
    const float* trans   = (const float*)d_in[4];
    const float* finalT  = (const float*)d_in[5];

    float* ws  = (float*)d_ws;     // [0..511] logZ, [512..1023] path score
    float* out = (float*)d_out;

    crf_main_kernel<<<NGRP + BB, BLKT, 0, stream>>>(emis, lengths, tags, prior,
                                                    trans, finalT, ws);
    reduce_mean_kernel<<<1, 512, 0, stream>>>(ws, out);
}

// Round 8
// 330.093 us; speedup vs baseline: 1.3901x; 1.0047x over previous
//
#include <hip/hip_runtime.h>

// CRF loss: mean over batch of (logZ - path_score).  B=512, T=1024, K=48.
//
// Forward: 16 sequences per block, 32 blocks x 256 threads (4 waves, one per
// SIMD -- consumer never shares issue slots with producers).
//   wave 0 (consumer): scaled linear-domain recurrence as 48x48 @ 48x16 MFMA
//     per step: Q' = (expT @ Q) .* expE_t, per-column log-scale c.
//     D-layout == B-layout for v_mfma_f32_16x16x16_bf16, so D feeds the next
//     step's B via per-lane mul + bf16 pack only. Emissions arrive from LDS
//     ALREADY EXPONENTIATED (r6 lesson: 12 quarter-rate v_exp/step choked
//     the serial wave).
//   waves 1..3 (producers): global_load_dwordx4 -> VGPR (deep vmcnt queue;
//     global_load_lds has a ~5-deep per-wave DMA queue, r5/r6 lesson),
//     v_exp on idle VALU, ds_write_b128 into a 16-slot LDS ring.
// Sync: LDS flag handshake, NO __syncthreads in the pipeline (its vmcnt(0)
// drain would expose HBM latency every phase). Per-producer phase counters +
// consumer progress counter; DS ops in-order per wave; threadfence_block for
// release ordering. Producer k gates on cons >= k-1 (16 slots = 2 phases);
// consumer k gates on all three producers >= k+1.
//
// R7 lesson (SQ_LDS_BANK_CONFLICT=371k): packed stride-12 granules put the
// consumer's 16 col-lanes on banks (16*col+4*grp)%32 -> two banks -> 8-way
// conflict on every ds_read_b128. Fix: STRIDE-13 layout, granule (seq,kg) at
// byte (seq*13+kg)*16 -> consumer bank (20*col+4*grp)%32, period 8 in col ->
// 2-way = free. Slot = 3328B, ring = 53KB.
// R7 lesson #2 (VGPR_Count=68): compiler never hoisted ds_reads across
// steps; ~120cyc LDS latency sat on the critical path every step. Fix:
// explicit 1-step X prefetch in the unrolled phase body.
//
// Ragged lengths: capture logZ at t == len-1 (ballot-guarded); per-column
// rescale every 8 steps bounds fp32/bf16 range.
// Path-score blocks (32..543) share the launch and overlap the forward waves.

#define BB    512
#define TT    1024
#define KK    48
#define GG    16
#define NGRP  32
#define NSLOT 16
#define SLOTB (13 * GG * 16)    // 3328 B per time-step slot (stride-13)
#define PHASE 8
#define NPROD 3
#define BLKT  256

typedef __attribute__((ext_vector_type(4))) short bf16x4;
typedef __attribute__((ext_vector_type(4))) float f32x4;

__device__ __forceinline__ f32x4 mfma16(bf16x4 a, bf16x4 b, f32x4 c) {
#if __has_builtin(__builtin_amdgcn_mfma_f32_16x16x16bf16_1k)
    return __builtin_amdgcn_mfma_f32_16x16x16bf16_1k(a, b, c, 0, 0, 0);
#else
    f32x4 d;
    asm volatile("v_mfma_f32_16x16x16_bf16 %0, %1, %2, %3"
                 : "=v"(d) : "v"(a), "v"(b), "v"(c));
    return d;
#endif
}

#if __has_builtin(__builtin_amdgcn_cvt_pk_bf16_f32)
typedef __attribute__((ext_vector_type(2))) __bf16 bf16x2_v;
__device__ __forceinline__ unsigned pk2(float lo, float hi) {
    union { bf16x2_v v; unsigned u; } x;
    x.v = __builtin_amdgcn_cvt_pk_bf16_f32(lo, hi);
    return x.u;
}
#else
__device__ __forceinline__ unsigned pk2(float lo, float hi) {
    return __builtin_amdgcn_perm(__float_as_uint(hi) + 0x8000u,
                                 __float_as_uint(lo) + 0x8000u,
                                 0x07060302u);
}
#endif
__device__ __forceinline__ bf16x4 pack4(float a, float b, float c, float d) {
    union { unsigned u[2]; bf16x4 v; } x;
    x.u[0] = pk2(a, b);
    x.u[1] = pk2(c, d);
    return x.v;
}

__device__ __forceinline__ float wave_reduce_sum(float v) {
    #pragma unroll
    for (int off = 32; off > 0; off >>= 1)
        v += __shfl_xor(v, off, 64);
    return v;
}

__global__ __launch_bounds__(BLKT, 1) void crf_main_kernel(
    const float* __restrict__ emis,    // [B,T,K]
    const int*   __restrict__ lengths, // [B]
    const int*   __restrict__ tags,    // [B,T]
    const float* __restrict__ prior,   // [K]
    const float* __restrict__ trans,   // [K,K] trans[dest][src]
    const float* __restrict__ finalT,  // [K]
    float*       __restrict__ ws)      // [0..511] logZ, [512..1023] path
{
    __shared__ __align__(16) unsigned char ring[NSLOT * SLOTB];  // 53 KB
    __shared__ int prodCnt[NPROD];
    __shared__ int consCnt;

    const int tid  = threadIdx.x;
    const int wv   = tid >> 6;
    const int lane = tid & 63;

    // ================= path-score blocks =================
    if (blockIdx.x >= NGRP) {
        const int b = blockIdx.x - NGRP;
        int len = lengths[b];
        len = (len < 1) ? 1 : (len > TT ? TT : len);
        const float* eb = emis + (size_t)b * TT * KK;
        const int*   tg = tags + (size_t)b * TT;
        float ps = 0.0f;
        for (int t = tid; t < len; t += BLKT) {
            int cur = tg[t];
            float ev = eb[(size_t)t * KK + cur];
            float tr = (t == 0) ? prior[cur] : trans[cur * KK + tg[t - 1]];
            ps += ev + tr;
        }
        ps = wave_reduce_sum(ps);
        float* red = (float*)ring;
        if (lane == 0) red[wv] = ps;
        __syncthreads();
        if (tid == 0)
            ws[BB + b] = red[0] + red[1] + red[2] + red[3] + finalT[tg[len - 1]];
        return;
    }

    // ================= forward blocks =================
    const int g = blockIdx.x;

    if (tid == 0) {
        prodCnt[0] = 0; prodCnt[1] = 0; prodCnt[2] = 0; consCnt = 0;
    }
    __syncthreads();   // one-time flag init

    // gmax computed identically by every wave
    int myLen = lengths[g * GG + (lane & 15)];
    myLen = (myLen < 1) ? 1 : (myLen > TT ? TT : myLen);
    int gmax = myLen;
    #pragma unroll
    for (int off = 32; off > 0; off >>= 1) {
        int o = __shfl_xor(gmax, off, 64);
        gmax = (o > gmax) ? o : gmax;
    }
    const int nsteps = gmax - 1;                 // steps t = 1..nsteps
    const int nphase = (nsteps + PHASE - 1) / PHASE;

    if (wv >= 1) {
        // ---------------- producer waves (1..3) ----------------
        // linear granule lidx = lane + 64j (j=0..2): seq = lidx/12, kg =
        // lidx%12. Global: seq-major packed (coalesced 192B runs). LDS:
        // stride-13 placement (seq*13+kg)*16.
        size_t go[3]; int lo16[3];
        #pragma unroll
        for (int j = 0; j < 3; ++j) {
            int lidx = lane + 64 * j;
            int s    = lidx / 12;
            int kg   = lidx - s * 12;
            go[j]    = (size_t)(g * GG + s) * (TT * KK) + kg * 4;
            lo16[j]  = (s * 13 + kg) * 16;
        }
        const int sA = wv - 1;       // slots sA, sA+3, sA+6 (skip if >=8)
        float4 L[9];

#define PLOAD(KP)                                                          \
        {                                                                  \
            _Pragma("unroll")                                              \
            for (int h = 0; h < 3; ++h) {                                  \
                int s = sA + 3 * h;                                        \
                if (s < PHASE) {                                           \
                    int t  = 1 + (KP) * PHASE + s;                         \
                    int tc = (t > nsteps) ? nsteps : t;                    \
                    _Pragma("unroll")                                      \
                    for (int j = 0; j < 3; ++j)                            \
                        L[h*3+j] = *reinterpret_cast<const float4*>(       \
                            emis + go[j] + (size_t)tc * KK);               \
                }                                                          \
            }                                                              \
        }

        PLOAD(0);
        volatile int* vc = &consCnt;
        for (int k = 0; k < nphase; ++k) {
            while (*vc < k - 1) __builtin_amdgcn_s_sleep(1);  // slot reuse gate
            asm volatile("" ::: "memory");
            #pragma unroll
            for (int h = 0; h < 3; ++h) {
                int s = sA + 3 * h;
                if (s < PHASE) {
                    int t = 1 + k * PHASE + s;
                    unsigned char* bp = &ring[(t & (NSLOT - 1)) * SLOTB];
                    #pragma unroll
                    for (int j = 0; j < 3; ++j) {
                        float4 l = L[h*3+j];
                        float4 e;
                        e.x = __expf(l.x); e.y = __expf(l.y);
                        e.z = __expf(l.z); e.w = __expf(l.w);
                        *reinterpret_cast<float4*>(bp + lo16[j]) = e;
                    }
                }
            }
            __threadfence_block();                 // release: writes -> flag
            if (lane == 0) *(volatile int*)&prodCnt[sA] = k + 1;
            PLOAD(k + 1);                          // next phase, in flight
        }
#undef PLOAD
        return;
    }

    // ---------------- consumer (MFMA) wave ----------------
    const int col   = lane & 15;
    const int grp   = lane >> 4;
    const int rbase = grp * 4;
    const int seq   = g * GG + col;
    const int lenn1 = myLen - 1;

    // A tiles: bf16(exp(trans)); A[m][k]: m = mt*16+col, k = kt*16+rbase+j
    bf16x4 A[3][3];
    #pragma unroll
    for (int mt = 0; mt < 3; ++mt) {
        #pragma unroll
        for (int kt = 0; kt < 3; ++kt) {
            float4 tv = *reinterpret_cast<const float4*>(
                trans + (size_t)(mt * 16 + col) * KK + kt * 16 + rbase);
            A[mt][kt] = pack4(__expf(tv.x), __expf(tv.y),
                              __expf(tv.z), __expf(tv.w));
        }
    }

    float expF[12];
    #pragma unroll
    for (int mt = 0; mt < 3; ++mt) {
        float4 fv = *reinterpret_cast<const float4*>(finalT + mt * 16 + rbase);
        expF[mt*4+0] = __expf(fv.x); expF[mt*4+1] = __expf(fv.y);
        expF[mt*4+2] = __expf(fv.z); expF[mt*4+3] = __expf(fv.w);
    }

    const float* ebase = emis + (size_t)seq * TT * KK + rbase;

    // init (t=0): w = exp(E0 + prior - c), c = per-column max
    float w[12];
    float c;
    float zcap = 0.0f;
    {
        float a0[12];
        #pragma unroll
        for (int mt = 0; mt < 3; ++mt) {
            float4 ev = *reinterpret_cast<const float4*>(ebase + mt * 16);
            float4 pv = *reinterpret_cast<const float4*>(prior + mt * 16 + rbase);
            a0[mt*4+0] = ev.x + pv.x;
            a0[mt*4+1] = ev.y + pv.y;
            a0[mt*4+2] = ev.z + pv.z;
            a0[mt*4+3] = ev.w + pv.w;
        }
        float mx = a0[0];
        #pragma unroll
        for (int r = 1; r < 12; ++r) mx = fmaxf(mx, a0[r]);
        mx = fmaxf(mx, __shfl_xor(mx, 16, 64));
        mx = fmaxf(mx, __shfl_xor(mx, 32, 64));
        c = mx;
        #pragma unroll
        for (int r = 0; r < 12; ++r) w[r] = __expf(a0[r] - c);
        if (__ballot(lenn1 == 0)) {
            float S = 0.0f;
            #pragma unroll
            for (int r = 0; r < 12; ++r) S = fmaf(w[r], expF[r], S);
            S += __shfl_xor(S, 16, 64);
            S += __shfl_xor(S, 32, 64);
            if (lenn1 == 0) zcap = c + __logf(S);
        }
    }

    bf16x4 Bt[3];
    Bt[0] = pack4(w[0], w[1], w[2],  w[3]);
    Bt[1] = pack4(w[4], w[5], w[6],  w[7]);
    Bt[2] = pack4(w[8], w[9], w[10], w[11]);

    // float offset of this lane's granules in a slot: (col*13 + grp)*4;
    // X1/X2 at +16/+32 floats (granule step 4 = 64B)
    const int foff = col * 52 + grp * 4;
    const f32x4 zero4 = {0.f, 0.f, 0.f, 0.f};
    volatile int* vp = prodCnt;

    for (int k = 0; k < nphase; ++k) {
        while (vp[0] < k + 1 || vp[1] < k + 1 || vp[2] < k + 1)
            __builtin_amdgcn_s_sleep(1);           // phase-k data ready
        asm volatile("" ::: "memory");
        const int t0 = 1 + k * PHASE;
        // prefetch first step's emissions
        const float* sp0 = reinterpret_cast<const float*>(
            &ring[(t0 & (NSLOT - 1)) * SLOTB]) + foff;
        float4 Xa = *reinterpret_cast<const float4*>(sp0);
        float4 Xb = *reinterpret_cast<const float4*>(sp0 + 16);
        float4 Xc = *reinterpret_cast<const float4*>(sp0 + 32);
        #pragma unroll
        for (int s8 = 0; s8 < PHASE; ++s8) {
            const int t = t0 + s8;                 // may exceed nsteps: harmless
            float4 X0 = Xa, X1 = Xb, X2 = Xc;
            if (s8 + 1 < PHASE) {                  // prefetch next step (SSA-renamed)
                const float* spn = reinterpret_cast<const float*>(
                    &ring[((t + 1) & (NSLOT - 1)) * SLOTB]) + foff;
                Xa = *reinterpret_cast<const float4*>(spn);
                Xb = *reinterpret_cast<const float4*>(spn + 16);
                Xc = *reinterpret_cast<const float4*>(spn + 32);
            }

            // Q' = expT @ Q : 9 MFMAs, 3 independent acc chains
            f32x4 D0 = mfma16(A[0][0], Bt[0], zero4);
            f32x4 D1 = mfma16(A[1][0], Bt[0], zero4);
            f32x4 D2 = mfma16(A[2][0], Bt[0], zero4);
            D0 = mfma16(A[0][1], Bt[1], D0);
            D1 = mfma16(A[1][1], Bt[1], D1);
            D2 = mfma16(A[2][1], Bt[1], D2);
            D0 = mfma16(A[0][2], Bt[2], D0);
            D1 = mfma16(A[1][2], Bt[2], D1);
            D2 = mfma16(A[2][2], Bt[2], D2);

            // emissions pre-exponentiated by producers: plain mul
            w[0]  = D0.x * X0.x;  w[1]  = D0.y * X0.y;
            w[2]  = D0.z * X0.z;  w[3]  = D0.w * X0.w;
            w[4]  = D1.x * X1.x;  w[5]  = D1.y * X1.y;
            w[6]  = D1.z * X1.z;  w[7]  = D1.w * X1.w;
            w[8]  = D2.x * X2.x;  w[9]  = D2.y * X2.y;
            w[10] = D2.z * X2.z;  w[11] = D2.w * X2.w;

            // per-column rescale: (t&7)==0 constant-folds to s8==7
            if ((t & 7) == 0) {
                float mx = w[0];
                #pragma unroll
                for (int r = 1; r < 12; ++r) mx = fmaxf(mx, w[r]);
                mx = fmaxf(mx, __shfl_xor(mx, 16, 64));
                mx = fmaxf(mx, __shfl_xor(mx, 32, 64));
                c += __logf(mx);
                float rm = __builtin_amdgcn_rcpf(mx);
                #pragma unroll
                for (int r = 0; r < 12; ++r) w[r] *= rm;
            }

            // capture finished columns (rare; ballot-guarded)
            if (__ballot(t == lenn1)) {
                float S = 0.0f;
                #pragma unroll
                for (int r = 0; r < 12; ++r) S = fmaf(w[r], expF[r], S);
                S += __shfl_xor(S, 16, 64);
                S += __shfl_xor(S, 32, 64);
                if (t == lenn1) zcap = c + __logf(S);
            }

            // repack state for next step's B operand
            Bt[0] = pack4(w[0], w[1], w[2],  w[3]);
            Bt[1] = pack4(w[4], w[5], w[6],  w[7]);
            Bt[2] = pack4(w[8], w[9], w[10], w[11]);
        }
        __threadfence_block();                    // reads done -> progress flag
        asm volatile("" ::: "memory");
        if (lane == 0) *(volatile int*)&consCnt = k + 1;
    }

    if (lane < GG) ws[seq] = zcap;   // 4 replicas agree; lanes 0..15 write
}

__global__ __launch_bounds__(512) void reduce_mean_kernel(
    const float* __restrict__ ws, float* __restrict__ out)
{
    __shared__ float sm[8];
    int tid = threadIdx.x;          // 512 threads = 8 waves
    float x = ws[tid] - ws[BB + tid];   // logZ_b - path_b
    x = wave_reduce_sum(x);
    if ((tid & 63) == 0) sm[tid >> 6] = x;
    __syncthreads();
    if (tid < 8) {
        float y = sm[tid];
        y += __shfl_xor(y, 1, 64);
        y += __shfl_xor(y, 2, 64);
        y += __shfl_xor(y, 4, 64);
        if (tid == 0) out[0] = y * (1.0f / 512.0f);
    }
}

extern "C" void kernel_launch(void* const* d_in, const int* in_sizes, int n_in,
                              void* d_out, int out_size, void* d_ws, size_t ws_size,
                              hipStream_t stream) {
    const float* emis    = (const float*)d_in[0];
    const int*   lengths = (const int*)  d_in[1];
    const int*   tags    = (const int*)  d_in[2];
    const float* prior   = (const float*)d_in[3];
    const float* trans   = (const float*)d_in[4];
    const float* finalT  = (const float*)d_in[5];

    float* ws  = (float*)d_ws;     // [0..511] logZ, [512..1023] path score
    float* out = (float*)d_out;

    crf_main_kernel<<<NGRP + BB, BLKT, 0, stream>>>(emis, lengths, tags, prior,
                                                    trans, finalT, ws);
    reduce_mean_kernel<<<1, 512, 0, stream>>>(ws, out);
}